// Round 3
// baseline (22.965 us; speedup 1.0000x reference)
//
#include <hip/hip_runtime.h>
#include <math.h>

#define B_TOT 16384
#define F_SP  26
#define F_DN  13
#define VOCAB 100000
#define EMB   16

// ---------------- Two-pass, XCD-L2-localized version ----------------
// Feature partition: group g (=blockIdx%8 -> XCD g) owns features {g, g+8, g+16, g+24}
// (4 features for g<2, 3 for g>=2). Each XCD's L2 caches only its ~4-5.5MB slice
// of fm_emb/lin_emb hot lines -> gathers become L2 hits across graph replays.
//
// ws layout: s_part[8][16384][16] floats, then sc_part[8][16384] floats.
#define S_PART_FLOATS   (8 * B_TOT * EMB)            // 2,097,152
#define SC_PART_FLOATS  (8 * B_TOT)                  // 131,072
#define WS_FLOATS       (S_PART_FLOATS + SC_PART_FLOATS)

// Kernel 1: per (sample, group) partials. 16 threads/sample (1 float of EMB each),
// 16 samples/block, grid = 8 groups x 1024 chunks = 8192 blocks.
__global__ __launch_bounds__(256) void fm_partial_kernel(
    const int*   __restrict__ sparse,    // [B, 26]
    const float* __restrict__ lin_emb,   // [26, 100000]
    const float* __restrict__ fm_emb,    // [26, 100000, 16]
    float*       __restrict__ s_part,    // [8][B][16]
    float*       __restrict__ sc_part)   // [8][B]
{
    const int gid   = blockIdx.x;
    const int g     = gid & 7;           // feature group == XCD (round-robin heuristic)
    const int chunk = gid >> 3;
    const int tid   = threadIdx.x;
    const int sloc  = tid >> 4;          // sample within block (0..15)
    const int l     = tid & 15;          // embedding dim lane
    const int b     = chunk * 16 + sloc;
    const int nf    = (g < 2) ? 4 : 3;   // features in this group

    // Lane l<nf loads the index for feature g+8*l of its sample (scattered 4B).
    int myidx = 0;
    if (l < nf)
        myidx = sparse[b * F_SP + g + 8 * l];

    const int v0 = __shfl(myidx, 0, 16);
    const int v1 = __shfl(myidx, 1, 16);
    const int v2 = __shfl(myidx, 2, 16);
    const int v3 = __shfl(myidx, 3, 16);

    // Each 16-lane cluster reads one full 64B fm row per feature (coalesced).
    const float* basep = fm_emb + l;
    const float e0 = basep[((size_t)(g)      * VOCAB + (size_t)v0) * EMB];
    const float e1 = basep[((size_t)(g + 8)  * VOCAB + (size_t)v1) * EMB];
    const float e2 = basep[((size_t)(g + 16) * VOCAB + (size_t)v2) * EMB];
    float e3 = 0.f;
    if (nf == 4)
        e3 = basep[((size_t)(g + 24) * VOCAB + (size_t)v3) * EMB];

    // First-order partial: lane l<nf gathers its feature's 1-d embedding.
    float lin = 0.f;
    if (l < nf)
        lin = lin_emb[(size_t)(g + 8 * l) * VOCAB + (size_t)myidx];

    const float s   = e0 + e1 + e2 + e3;                      // partial sum vec (dim l)
    const float ssq = e0*e0 + e1*e1 + e2*e2 + e3*e3;          // partial sum of squares

    // Scalar partial: sum over this group's (f,e) of -0.5*e^2  +  lin terms.
    float t = -0.5f * ssq + lin;
    t += __shfl_xor(t, 1);
    t += __shfl_xor(t, 2);
    t += __shfl_xor(t, 4);
    t += __shfl_xor(t, 8);

    s_part[(((size_t)g << 14) + b) * EMB + l] = s;            // coalesced 64B/sample
    if (l == 0)
        sc_part[((size_t)g << 14) + b] = t;
}

// Kernel 2: reduce 8 groups, add dense linear, apply both sigmoid heads.
__global__ __launch_bounds__(256) void fm_finish_kernel(
    const float* __restrict__ s_part,
    const float* __restrict__ sc_part,
    const float* __restrict__ dense,     // [B, 13]
    const float* __restrict__ ldW,       // [13]
    const float* __restrict__ ldB,       // [1]
    const float* __restrict__ fW, const float* __restrict__ fB,
    const float* __restrict__ lW, const float* __restrict__ lB,
    float*       __restrict__ out)       // [B, 2]
{
    const int tid  = threadIdx.x;
    const int sloc = tid >> 4;
    const int l    = tid & 15;
    const int b    = blockIdx.x * 16 + sloc;

    float s = 0.f;
    #pragma unroll
    for (int g = 0; g < 8; ++g)
        s += s_part[(((size_t)g << 14) + b) * EMB + l];

    float t = 0.5f * s * s;                                   // 0.5 * sum_e s_e^2
    if (l < 8)
        t += sc_part[((size_t)l << 14) + b];                  // group scalars
    if (l < F_DN)
        t += dense[b * F_DN + l] * ldW[l];                    // dense linear
    if (l == 0)
        t += ldB[0];

    t += __shfl_xor(t, 1);
    t += __shfl_xor(t, 2);
    t += __shfl_xor(t, 4);
    t += __shfl_xor(t, 8);

    if (l == 0) {
        const float finish = 1.f / (1.f + expf(-(t * fW[0] + fB[0])));
        const float like   = 1.f / (1.f + expf(-(t * lW[0] + lB[0])));
        *reinterpret_cast<float2*>(&out[b * 2]) = make_float2(finish, like);
    }
}

// ---------------- Fallback: round-2 single-pass kernel ----------------
__global__ __launch_bounds__(256) void fm_mtl_kernel(
    const int*   __restrict__ sparse, const float* __restrict__ dense,
    const float* __restrict__ ldW, const float* __restrict__ ldB,
    const float* __restrict__ lin_emb, const float* __restrict__ fm_emb,
    const float* __restrict__ fW, const float* __restrict__ fB,
    const float* __restrict__ lW, const float* __restrict__ lB,
    float* __restrict__ out)
{
    __shared__ int s_idx[16 * F_SP];
    const int tid = threadIdx.x;
    const int block_base = blockIdx.x * 16;
    for (int i = tid; i < 16 * F_SP; i += 256)
        s_idx[i] = sparse[block_base * F_SP + i];
    __syncthreads();

    const int sloc = tid >> 4, g = tid & 15, d = g & 7, fh = g >> 3;
    const int b = block_base + sloc;
    const int* idx = &s_idx[sloc * F_SP];

    float lin = lin_emb[(size_t)g * VOCAB + (size_t)idx[g]];
    if (g < 10) lin += lin_emb[(size_t)(g + 16) * VOCAB + (size_t)idx[g + 16]];
    if (g < F_DN) lin += dense[b * F_DN + g] * ldW[g];
    if (g == 0) lin += ldB[0];

    float2 s = make_float2(0.f, 0.f);
    float ssq = 0.f;
    const int f0 = fh * 13;
    #pragma unroll
    for (int k = 0; k < 13; ++k) {
        const int f = f0 + k, v = idx[f];
        const float2 e = *reinterpret_cast<const float2*>(
            &fm_emb[((size_t)f * VOCAB + (size_t)v) * EMB + d * 2]);
        s.x += e.x; s.y += e.y;
        ssq += e.x * e.x + e.y * e.y;
    }
    s.x += __shfl_xor(s.x, 8);
    s.y += __shfl_xor(s.y, 8);
    const float p2 = s.x * s.x + s.y * s.y;
    float r = 0.25f * p2 - 0.5f * ssq + lin;
    r += __shfl_xor(r, 1); r += __shfl_xor(r, 2);
    r += __shfl_xor(r, 4); r += __shfl_xor(r, 8);
    if (g == 0) {
        const float finish = 1.f / (1.f + expf(-(r * fW[0] + fB[0])));
        const float like   = 1.f / (1.f + expf(-(r * lW[0] + lB[0])));
        *reinterpret_cast<float2*>(&out[b * 2]) = make_float2(finish, like);
    }
}

extern "C" void kernel_launch(void* const* d_in, const int* in_sizes, int n_in,
                              void* d_out, int out_size, void* d_ws, size_t ws_size,
                              hipStream_t stream) {
    const int*   sparse  = (const int*)  d_in[0];
    const float* dense   = (const float*)d_in[1];
    const float* ldW     = (const float*)d_in[2];
    const float* ldB     = (const float*)d_in[3];
    const float* lin_emb = (const float*)d_in[4];
    const float* fm_emb  = (const float*)d_in[5];
    const float* fW      = (const float*)d_in[6];
    const float* fB      = (const float*)d_in[7];
    const float* lW      = (const float*)d_in[8];
    const float* lB      = (const float*)d_in[9];
    float* out = (float*)d_out;

    if (ws_size >= (size_t)WS_FLOATS * sizeof(float)) {
        float* s_part  = (float*)d_ws;
        float* sc_part = s_part + S_PART_FLOATS;
        fm_partial_kernel<<<dim3(8 * (B_TOT / 16)), dim3(256), 0, stream>>>(
            sparse, lin_emb, fm_emb, s_part, sc_part);
        fm_finish_kernel<<<dim3(B_TOT / 16), dim3(256), 0, stream>>>(
            s_part, sc_part, dense, ldW, ldB, fW, fB, lW, lB, out);
    } else {
        fm_mtl_kernel<<<dim3(B_TOT / 16), dim3(256), 0, stream>>>(
            sparse, dense, ldW, ldB, lin_emb, fm_emb, fW, fB, lW, lB, out);
    }
}